// Round 7
// baseline (4583.399 us; speedup 1.0000x reference)
//
#include <hip/hip_runtime.h>
#include <hip/hip_bf16.h>

// Axial rel-pos attention, MI355X gfx950.
// Shapes: W=192 seq, B=384 batch (=2*192), C=128, 8 heads, hd=16.

typedef unsigned short u16;
typedef short bf16x8 __attribute__((ext_vector_type(8)));
typedef float f32x4 __attribute__((ext_vector_type(4)));
typedef float f32x16 __attribute__((ext_vector_type(16)));

__device__ inline u16 f2bf(float f) {
    union { float f; unsigned u; } a; a.f = f;
    unsigned u = a.u;
    unsigned r = u + 0x7FFFu + ((u >> 16) & 1u);   // RNE
    return (u16)(r >> 16);
}
__device__ inline unsigned cvt_pk_bf16(float lo, float hi) {
    unsigned r;
    asm("v_cvt_pk_bf16_f32 %0, %1, %2" : "=v"(r) : "v"(lo), "v"(hi));
    return r;
}
// LDS float atomic add via the DS pipe. Generic pointers to __shared__ on
// gfx9+ are (aperture_hi<<32)|lds_byte_offset, so the low 32 bits are the
// DS address. No return value; drained by the waitcnt before s_barrier.
__device__ inline void lds_add(float* p, float v) {
    unsigned off = (unsigned)(uintptr_t)p;
    asm volatile("ds_add_f32 %0, %1" :: "v"(off), "v"(v) : "memory");
}

// ---------------- LayerNorm + transpose (feat[w,s*192+h] -> x2[h,s*192+w]) ----
__global__ __launch_bounds__(256) void ln_kernel(const float* __restrict__ feat,
                                                 const float* __restrict__ g,
                                                 const float* __restrict__ bta,
                                                 u16* __restrict__ x2) {
    int wid = threadIdx.x >> 6, lane = threadIdx.x & 63;
    int r = blockIdx.x * 4 + wid;                 // 0..73727
    const float* row = feat + (size_t)r * 128;
    float v0 = row[lane], v1 = row[lane + 64];
    float s = v0 + v1;
    for (int m = 1; m < 64; m <<= 1) s += __shfl_xor(s, m);
    float mean = s * (1.0f / 128.0f);
    float d0 = v0 - mean, d1 = v1 - mean;
    float vs = d0 * d0 + d1 * d1;
    for (int m = 1; m < 64; m <<= 1) vs += __shfl_xor(vs, m);
    float rstd = rsqrtf(vs * (1.0f / 128.0f) + 1e-5f);
    int w = r / 384, rem = r % 384;               // rem = s*192 + h
    int out_r = (rem % 192) * 384 + (rem / 192) * 192 + w;
    u16* orow = x2 + (size_t)out_r * 128;
    orow[lane]      = f2bf(d0 * rstd * g[lane] + bta[lane]);
    orow[lane + 64] = f2bf(d1 * rstd * g[lane + 64] + bta[lane + 64]);
}

// ---------------- pos-embedding projection: P = pos @ w_in[:256].T + b ---------
// qr[e][d][j] = P[d, e*16+j]*0.25 ; kr[e][d][j] = P[d, 128+e*16+j]; row 383 = 0.
__global__ __launch_bounds__(256) void posproj_kernel(const float* __restrict__ pos,
                                                      const float* __restrict__ w_in,
                                                      const float* __restrict__ b_in,
                                                      u16* __restrict__ qr,
                                                      u16* __restrict__ kr) {
    int d = blockIdx.x, t = threadIdx.x;
    if (d == 383) {
        if (t < 128)      { int e = t >> 4,  j = t & 15;  qr[(e * 384 + 383) * 16 + j] = 0; }
        else              { int t2 = t - 128; int e = t2 >> 4, j = t2 & 15; kr[(e * 384 + 383) * 16 + j] = 0; }
        return;
    }
    __shared__ float prow[128];
    if (t < 128) prow[t] = pos[d * 128 + t];
    __syncthreads();
    const float* wrow = w_in + t * 128;
    float acc = b_in[t];
    #pragma unroll 8
    for (int k = 0; k < 128; ++k) acc += prow[k] * wrow[k];
    int which = t >> 7, e = (t >> 4) & 7, j = t & 15;
    if (which == 0) qr[(e * 384 + d) * 16 + j] = f2bf(acc * 0.25f);
    else            kr[(e * 384 + d) * 16 + j] = f2bf(acc);
}

// ---------------- QKV GEMM: [73728,128]bf16 @ w_in^T[128,384] + b -------------
// Output scatter to Q/K/V [batch][head][seq][16] bf16, Q pre-scaled by 0.25.
__global__ __launch_bounds__(256) void qkv_gemm(const u16* __restrict__ X,
                                                const float* __restrict__ Wn,
                                                const float* __restrict__ bias,
                                                u16* __restrict__ Qo,
                                                u16* __restrict__ Ko,
                                                u16* __restrict__ Vo) {
    __shared__ u16 a_lds[128][136];
    __shared__ u16 w_lds[64][136];
    int tid = threadIdx.x;
    int m0 = blockIdx.y * 128, n0 = blockIdx.x * 64;
    #pragma unroll
    for (int i = 0; i < 8; ++i) {
        int idx = tid + 256 * i;
        int row = idx >> 4, c8 = (idx & 15) * 8;
        *(int4*)&a_lds[row][c8] = *(const int4*)&X[(size_t)(m0 + row) * 128 + c8];
    }
    #pragma unroll
    for (int i = 0; i < 8; ++i) {
        int idx = tid + 256 * i;
        int row = idx >> 5, c4 = (idx & 31) * 4;
        float4 f = *(const float4*)&Wn[(size_t)(n0 + row) * 128 + c4];
        uint2 p;
        p.x = (unsigned)f2bf(f.x) | ((unsigned)f2bf(f.y) << 16);
        p.y = (unsigned)f2bf(f.z) | ((unsigned)f2bf(f.w) << 16);
        *(uint2*)&w_lds[row][c4] = p;
    }
    __syncthreads();
    int lane = tid & 63, wid = tid >> 6;
    int wr = (wid >> 1) * 64, wc = (wid & 1) * 32;
    int kg = lane >> 4, l15 = lane & 15;
    f32x4 acc[4][2];
    #pragma unroll
    for (int i = 0; i < 4; ++i)
        #pragma unroll
        for (int j = 0; j < 2; ++j) acc[i][j] = (f32x4){0.f, 0.f, 0.f, 0.f};
    #pragma unroll
    for (int kk = 0; kk < 4; ++kk) {
        int kof = kk * 32 + kg * 8;
        bf16x8 a[4], b[2];
        #pragma unroll
        for (int i = 0; i < 4; ++i) a[i] = *(const bf16x8*)&a_lds[wr + i * 16 + l15][kof];
        #pragma unroll
        for (int j = 0; j < 2; ++j) b[j] = *(const bf16x8*)&w_lds[wc + j * 16 + l15][kof];
        #pragma unroll
        for (int i = 0; i < 4; ++i)
            #pragma unroll
            for (int j = 0; j < 2; ++j)
                acc[i][j] = __builtin_amdgcn_mfma_f32_16x16x32_bf16(a[i], b[j], acc[i][j], 0, 0, 0);
    }
    #pragma unroll
    for (int i = 0; i < 4; ++i)
        #pragma unroll
        for (int j = 0; j < 2; ++j) {
            int col_g = n0 + wc + j * 16 + l15;
            float bv = bias[col_g];
            int which = col_g >> 7, e = (col_g >> 4) & 7, d = col_g & 15;
            u16* dst = which == 0 ? Qo : (which == 1 ? Ko : Vo);
            float scl = which == 0 ? 0.25f : 1.0f;
            #pragma unroll
            for (int ii = 0; ii < 4; ++ii) {
                int row_g = m0 + wr + i * 16 + kg * 4 + ii;
                int batch = row_g % 384, sq = row_g / 384;
                dst[((size_t)(batch * 8 + e) * 192 + sq) * 16 + d] = f2bf((acc[i][j][ii] + bv) * scl);
            }
        }
}

// ---------------- fused rel-pos attention per (batch, head, w-half) -----------
// scores[w][v] = Q[w]·K[v] + Q[w]·kr[w-v+191] + K[v]·qr[w-v+191]
// v chunked 3x64 (no-max softmax => exact chunked accumulation).
// Per chunk: ONE scatter phase (A+B+C, 23 MFMA tiles, ds_add_f32 into zeroed
// sc) | bar | exp+pack->Pb (+re-zero sc, rsum+=) | bar | PV (waves 0-5,
// register O-acc) overlapping next chunk's scatter.
// sc rows 96..99 / cols 64..67 are per-lane-distinct OOB dump slots.
__global__ __launch_bounds__(512, 6) void attn_kernel(const u16* __restrict__ Qg,
                                                      const u16* __restrict__ Kg,
                                                      const u16* __restrict__ Vg,
                                                      const u16* __restrict__ qr_g,
                                                      const u16* __restrict__ kr_g,
                                                      u16* __restrict__ Og) {
    __shared__ float sc[100][68];   // 27200 B
    __shared__ u16 Pb[96][72];      // 13824 B packed P chunk (bf16)
    __shared__ u16 Vt[16][200];     // 6400 B
    __shared__ float rsum[96];
    int tid = threadIdx.x, lane = tid & 63, wid = tid >> 6;
    int half = blockIdx.x, e = blockIdx.y, b = blockIdx.z;
    int w0 = half * 96;
    size_t base = ((size_t)b * 8 + e) * 192 * 16;
    float* scf = &sc[0][0];

    // stage V^T (16 x 192), zero sc + rsum
    #pragma unroll
    for (int i = 0; i < 6; ++i) { int idx = tid + 512 * i;
        Vt[idx & 15][idx >> 4] = Vg[base + idx]; }
    #pragma unroll
    for (int i = 0; i < 14; ++i) { int idx = tid + 512 * i;
        if (idx < 6800) scf[idx] = 0.f; }
    if (tid < 96) rsum[tid] = 0.f;
    __syncthreads();

    int lo = lane & 31, hi = lane >> 5, hi8 = hi * 8;
    int l15 = lane & 15, kg = lane >> 4;
    const u16* Qrow  = Qg + base;
    const u16* Krow  = Kg + base;
    const u16* krrow = kr_g + (size_t)e * 384 * 16;
    const u16* qrrow = qr_g + (size_t)e * 384 * 16;
    f32x4 oacc = (f32x4){0.f, 0.f, 0.f, 0.f};

    for (int ch = 0; ch < 3; ++ch) {
        int v0 = ch * 64;
        // ---- phase 1: 23 tiles (6 A + 9 B + 8 C), all ds_add_f32 scatter ----
        #pragma unroll
        for (int it = 0; it < 3; ++it) {
            int t = wid + 8 * it;
            if (t < 6) {                       // A: (Q,K) -> reg->w, lane->v
                int wt = t >> 1, vt = t & 1;
                bf16x8 aq = *(const bf16x8*)(Qrow + (size_t)(w0 + wt * 32 + lo) * 16 + hi8);
                bf16x8 bk = *(const bf16x8*)(Krow + (size_t)(v0 + vt * 32 + lo) * 16 + hi8);
                f32x16 acc = {};
                acc = __builtin_amdgcn_mfma_f32_32x32x16_bf16(aq, bk, acc, 0, 0, 0);
                int r0 = wt * 32 + 4 * hi, c0 = vt * 32 + lo;
                #pragma unroll
                for (int ii = 0; ii < 16; ++ii) {
                    const int rr = (ii & 3) + 8 * (ii >> 2);
                    lds_add(&sc[r0 + rr][c0], acc[ii]);
                }
            } else if (t < 15) {               // B: (kr,Q) -> reg->d, lane->w
                int u = t - 6; int wt = u / 3, dt = u % 3;
                int D0 = w0 + wt * 32 - v0 + 128 + dt * 32;
                bf16x8 akr = *(const bf16x8*)(krrow + (size_t)(D0 + lo) * 16 + hi8);
                bf16x8 bq  = *(const bf16x8*)(Qrow + (size_t)(w0 + wt * 32 + lo) * 16 + hi8);
                f32x16 acc = {};
                acc = __builtin_amdgcn_mfma_f32_32x32x16_bf16(akr, bq, acc, 0, 0, 0);
                int cb = lo + 63 - 32 * dt - 4 * hi;     // c = cb - rr
                int row = wt * 32 + lo;
                if (dt == 1) {
                    #pragma unroll
                    for (int ii = 0; ii < 16; ++ii) {
                        const int rr = (ii & 3) + 8 * (ii >> 2);
                        lds_add(&sc[row][cb - rr], acc[ii]);
                    }
                } else {
                    #pragma unroll
                    for (int ii = 0; ii < 16; ++ii) {
                        const int rr = (ii & 3) + 8 * (ii >> 2);
                        int c = cb - rr;
                        int col = ((unsigned)c < 64u) ? c : (64 + (rr & 3));
                        lds_add(&sc[row][col], acc[ii]);
                    }
                }
            } else if (t < 23) {               // C: (qr,K) -> reg->d, lane->v
                int u = t - 15; int vt = u >> 2, dt = u & 3;
                int V0 = v0 + vt * 32;
                int D0 = w0 - V0 + 160 + dt * 32;
                bf16x8 aqr = *(const bf16x8*)(qrrow + (size_t)(D0 + lo) * 16 + hi8);
                bf16x8 bk  = *(const bf16x8*)(Krow + (size_t)(V0 + lo) * 16 + hi8);
                f32x16 acc = {};
                acc = __builtin_amdgcn_mfma_f32_32x32x16_bf16(aqr, bk, acc, 0, 0, 0);
                int c = vt * 32 + lo;
                int rb = 32 * dt - 31 + lo + 4 * hi;     // r = rb + rr
                if (dt == 1 || dt == 2) {
                    #pragma unroll
                    for (int ii = 0; ii < 16; ++ii) {
                        const int rr = (ii & 3) + 8 * (ii >> 2);
                        lds_add(&sc[rb + rr][c], acc[ii]);
                    }
                } else {
                    #pragma unroll
                    for (int ii = 0; ii < 16; ++ii) {
                        const int rr = (ii & 3) + 8 * (ii >> 2);
                        int r = rb + rr;
                        int rowi = ((unsigned)r < 96u) ? r : (96 + (rr & 3));
                        lds_add(&sc[rowi][c], acc[ii]);
                    }
                }
            }
        }
        __syncthreads();

        // ---- phase 2: exp + pack -> Pb, re-zero sc, rsum += ----
        {
            int r = tid >> 2, j = tid & 3;
            if (r < 96) {
                float* srow = &sc[r][j * 16];
                f32x4 X0 = *(const f32x4*)&srow[0];
                f32x4 X1 = *(const f32x4*)&srow[4];
                f32x4 X2 = *(const f32x4*)&srow[8];
                f32x4 X3 = *(const f32x4*)&srow[12];
                f32x4 Z = (f32x4){0.f, 0.f, 0.f, 0.f};
                *(f32x4*)&srow[0] = Z; *(f32x4*)&srow[4] = Z;
                *(f32x4*)&srow[8] = Z; *(f32x4*)&srow[12] = Z;
                float xs[16];
                #pragma unroll
                for (int k = 0; k < 4; ++k) {
                    xs[k]      = __expf(X0[k]);
                    xs[4 + k]  = __expf(X1[k]);
                    xs[8 + k]  = __expf(X2[k]);
                    xs[12 + k] = __expf(X3[k]);
                }
                float sum = 0.f;
                #pragma unroll
                for (int k = 0; k < 16; ++k) sum += xs[k];
                unsigned pk[8];
                #pragma unroll
                for (int k = 0; k < 8; ++k) pk[k] = cvt_pk_bf16(xs[2 * k], xs[2 * k + 1]);
                unsigned* prow = (unsigned*)&Pb[r][j * 16];
                *(uint4*)prow       = *(uint4*)&pk[0];
                *((uint4*)prow + 1) = *(uint4*)&pk[4];
                sum += __shfl_xor(sum, 1);
                sum += __shfl_xor(sum, 2);
                if (j == 0) rsum[r] += sum;
            }
        }
        __syncthreads();

        // ---- phase 3: PV (waves 0..5), overlaps next chunk's scatter ----
        if (wid < 6) {
            #pragma unroll
            for (int kt = 0; kt < 2; ++kt) {
                bf16x8 a  = *(const bf16x8*)&Pb[wid * 16 + l15][kt * 32 + kg * 8];
                bf16x8 bb = *(const bf16x8*)&Vt[l15][v0 + kt * 32 + kg * 8];
                oacc = __builtin_amdgcn_mfma_f32_16x16x32_bf16(a, bb, oacc, 0, 0, 0);
            }
        }
        // no barrier: next phase-1 touches only sc (settled); phase-2 of the
        // next chunk (which rewrites Pb) is ordered behind the next barrier.
    }

    if (wid < 6) {
        #pragma unroll
        for (int ii = 0; ii < 4; ++ii) {
            int wl = wid * 16 + kg * 4 + ii;
            float val = oacc[ii] * (1.0f / rsum[wl]);
            Og[((size_t)(w0 + wl) * 384 + b) * 128 + e * 16 + l15] = f2bf(val);
        }
    }
}

// ---------------- output projection GEMM -------------------------------------
// MODE 0: x1[(w*384+s*192+h)] = O_row(h*384+s*192+w) @ w_out^T + b   (bf16)
// MODE 1: out[row] = O_row @ w_out^T + b + feat[row]                 (fp32)
template <int MODE>
__global__ __launch_bounds__(256) void outproj_gemm(const u16* __restrict__ X,
                                                    const float* __restrict__ Wn,
                                                    const float* __restrict__ bias,
                                                    const float* __restrict__ feat,
                                                    u16* __restrict__ x1o,
                                                    float* __restrict__ outp) {
    __shared__ u16 a_lds[128][136];
    __shared__ u16 w_lds[64][136];
    int tid = threadIdx.x;
    int m0 = blockIdx.y * 128, n0 = blockIdx.x * 64;
    #pragma unroll
    for (int i = 0; i < 8; ++i) {
        int idx = tid + 256 * i;
        int row = idx >> 4, c8 = (idx & 15) * 8;
        *(int4*)&a_lds[row][c8] = *(const int4*)&X[(size_t)(m0 + row) * 128 + c8];
    }
    #pragma unroll
    for (int i = 0; i < 8; ++i) {
        int idx = tid + 256 * i;
        int row = idx >> 5, c4 = (idx & 31) * 4;
        float4 f = *(const float4*)&Wn[(size_t)(n0 + row) * 128 + c4];
        uint2 p;
        p.x = (unsigned)f2bf(f.x) | ((unsigned)f2bf(f.y) << 16);
        p.y = (unsigned)f2bf(f.z) | ((unsigned)f2bf(f.w) << 16);
        *(uint2*)&w_lds[row][c4] = p;
    }
    __syncthreads();
    int lane = tid & 63, wid = tid >> 6;
    int wr = (wid >> 1) * 64, wc = (wid & 1) * 32;
    int kg = lane >> 4, l15 = lane & 15;
    f32x4 acc[4][2];
    #pragma unroll
    for (int i = 0; i < 4; ++i)
        #pragma unroll
        for (int j = 0; j < 2; ++j) acc[i][j] = (f32x4){0.f, 0.f, 0.f, 0.f};
    #pragma unroll
    for (int kk = 0; kk < 4; ++kk) {
        int kof = kk * 32 + kg * 8;
        bf16x8 a[4], b[2];
        #pragma unroll
        for (int i = 0; i < 4; ++i) a[i] = *(const bf16x8*)&a_lds[wr + i * 16 + l15][kof];
        #pragma unroll
        for (int j = 0; j < 2; ++j) b[j] = *(const bf16x8*)&w_lds[wc + j * 16 + l15][kof];
        #pragma unroll
        for (int i = 0; i < 4; ++i)
            #pragma unroll
            for (int j = 0; j < 2; ++j)
                acc[i][j] = __builtin_amdgcn_mfma_f32_16x16x32_bf16(a[i], b[j], acc[i][j], 0, 0, 0);
    }
    #pragma unroll
    for (int i = 0; i < 4; ++i)
        #pragma unroll
        for (int j = 0; j < 2; ++j) {
            int col_g = n0 + wc + j * 16 + l15;
            float bv = bias[col_g];
            #pragma unroll
            for (int ii = 0; ii < 4; ++ii) {
                int row_g = m0 + wr + i * 16 + kg * 4 + ii;
                float val = acc[i][j][ii] + bv;
                if (MODE == 0) {
                    int h = row_g / 384, rem = row_g % 384, s2 = rem / 192, w = rem % 192;
                    x1o[((size_t)(w * 384 + s2 * 192 + h)) * 128 + col_g] = f2bf(val);
                } else {
                    size_t o = (size_t)row_g * 128 + col_g;
                    outp[o] = val + feat[o];
                }
            }
        }
}

extern "C" void kernel_launch(void* const* d_in, const int* in_sizes, int n_in,
                              void* d_out, int out_size, void* d_ws, size_t ws_size,
                              hipStream_t stream) {
    const float* feat   = (const float*)d_in[0];
    const float* pos    = (const float*)d_in[1];
    const float* pos_y  = (const float*)d_in[2];
    const float* ln_w   = (const float*)d_in[3];
    const float* ln_b   = (const float*)d_in[4];
    const float* w_in1  = (const float*)d_in[5];
    const float* b_in1  = (const float*)d_in[6];
    const float* w_out1 = (const float*)d_in[7];
    const float* b_out1 = (const float*)d_in[8];
    const float* w_in2  = (const float*)d_in[9];
    const float* b_in2  = (const float*)d_in[10];
    const float* w_out2 = (const float*)d_in[11];
    const float* b_out2 = (const float*)d_in[12];
    float* out = (float*)d_out;

    char* ws = (char*)d_ws;
    const size_t R = (size_t)73728 * 128;   // 9,437,184 elements
    u16* x2 = (u16*)ws; ws += R * 2;
    u16* x1 = (u16*)ws; ws += R * 2;
    u16* Q  = (u16*)ws; ws += R * 2;
    u16* K  = (u16*)ws; ws += R * 2;
    u16* V  = (u16*)ws; ws += R * 2;
    u16* O  = (u16*)ws; ws += R * 2;
    u16* qr = (u16*)ws; ws += (size_t)8 * 384 * 16 * 2;
    u16* kr = (u16*)ws; ws += (size_t)8 * 384 * 16 * 2;

    // ---- layer 2 (vertical axis) ----
    ln_kernel<<<18432, 256, 0, stream>>>(feat, ln_w, ln_b, x2);
    posproj_kernel<<<384, 256, 0, stream>>>(pos_y, w_in2, b_in2, qr, kr);
    qkv_gemm<<<dim3(6, 576), 256, 0, stream>>>(x2, w_in2, b_in2, Q, K, V);
    attn_kernel<<<dim3(2, 8, 384), 512, 0, stream>>>(Q, K, V, qr, kr, O);
    outproj_gemm<0><<<dim3(2, 576), 256, 0, stream>>>(O, w_out2, b_out2, nullptr, x1, nullptr);
    // ---- layer 1 (horizontal axis) ----
    posproj_kernel<<<384, 256, 0, stream>>>(pos, w_in1, b_in1, qr, kr);
    qkv_gemm<<<dim3(6, 576), 256, 0, stream>>>(x1, w_in1, b_in1, Q, K, V);
    attn_kernel<<<dim3(2, 8, 384), 512, 0, stream>>>(Q, K, V, qr, kr, O);
    outproj_gemm<1><<<dim3(2, 576), 256, 0, stream>>>(O, w_out1, b_out1, feat, nullptr, out);
}

// Round 8
// 436.596 us; speedup vs baseline: 10.4980x; 10.4980x over previous
//
#include <hip/hip_runtime.h>
#include <hip/hip_bf16.h>

// Axial rel-pos attention, MI355X gfx950.
// Shapes: W=192 seq, B=384 batch (=2*192), C=128, 8 heads, hd=16.

typedef unsigned short u16;
typedef short bf16x8 __attribute__((ext_vector_type(8)));
typedef float f32x4 __attribute__((ext_vector_type(4)));
typedef float f32x16 __attribute__((ext_vector_type(16)));

__device__ inline u16 f2bf(float f) {
    union { float f; unsigned u; } a; a.f = f;
    unsigned u = a.u;
    unsigned r = u + 0x7FFFu + ((u >> 16) & 1u);   // RNE
    return (u16)(r >> 16);
}
__device__ inline unsigned cvt_pk_bf16(float lo, float hi) {
    unsigned r;
    asm("v_cvt_pk_bf16_f32 %0, %1, %2" : "=v"(r) : "v"(lo), "v"(hi));
    return r;
}

// ---------------- LayerNorm + transpose (feat[w,s*192+h] -> x2[h,s*192+w]) ----
__global__ __launch_bounds__(256) void ln_kernel(const float* __restrict__ feat,
                                                 const float* __restrict__ g,
                                                 const float* __restrict__ bta,
                                                 u16* __restrict__ x2) {
    int wid = threadIdx.x >> 6, lane = threadIdx.x & 63;
    int r = blockIdx.x * 4 + wid;                 // 0..73727
    const float* row = feat + (size_t)r * 128;
    float v0 = row[lane], v1 = row[lane + 64];
    float s = v0 + v1;
    for (int m = 1; m < 64; m <<= 1) s += __shfl_xor(s, m);
    float mean = s * (1.0f / 128.0f);
    float d0 = v0 - mean, d1 = v1 - mean;
    float vs = d0 * d0 + d1 * d1;
    for (int m = 1; m < 64; m <<= 1) vs += __shfl_xor(vs, m);
    float rstd = rsqrtf(vs * (1.0f / 128.0f) + 1e-5f);
    int w = r / 384, rem = r % 384;               // rem = s*192 + h
    int out_r = (rem % 192) * 384 + (rem / 192) * 192 + w;
    u16* orow = x2 + (size_t)out_r * 128;
    orow[lane]      = f2bf(d0 * rstd * g[lane] + bta[lane]);
    orow[lane + 64] = f2bf(d1 * rstd * g[lane + 64] + bta[lane + 64]);
}

// ---------------- pos-embedding projection: P = pos @ w_in[:256].T + b ---------
// qr[e][d][j] = P[d, e*16+j]*0.25 ; kr[e][d][j] = P[d, 128+e*16+j]; row 383 = 0.
__global__ __launch_bounds__(256) void posproj_kernel(const float* __restrict__ pos,
                                                      const float* __restrict__ w_in,
                                                      const float* __restrict__ b_in,
                                                      u16* __restrict__ qr,
                                                      u16* __restrict__ kr) {
    int d = blockIdx.x, t = threadIdx.x;
    if (d == 383) {
        if (t < 128)      { int e = t >> 4,  j = t & 15;  qr[(e * 384 + 383) * 16 + j] = 0; }
        else              { int t2 = t - 128; int e = t2 >> 4, j = t2 & 15; kr[(e * 384 + 383) * 16 + j] = 0; }
        return;
    }
    __shared__ float prow[128];
    if (t < 128) prow[t] = pos[d * 128 + t];
    __syncthreads();
    const float* wrow = w_in + t * 128;
    float acc = b_in[t];
    #pragma unroll 8
    for (int k = 0; k < 128; ++k) acc += prow[k] * wrow[k];
    int which = t >> 7, e = (t >> 4) & 7, j = t & 15;
    if (which == 0) qr[(e * 384 + d) * 16 + j] = f2bf(acc * 0.25f);
    else            kr[(e * 384 + d) * 16 + j] = f2bf(acc);
}

// ---------------- QKV GEMM: [73728,128]bf16 @ w_in^T[128,384] + b -------------
// Output scatter to Q/K/V [batch][head][seq][16] bf16, Q pre-scaled by 0.25.
__global__ __launch_bounds__(256) void qkv_gemm(const u16* __restrict__ X,
                                                const float* __restrict__ Wn,
                                                const float* __restrict__ bias,
                                                u16* __restrict__ Qo,
                                                u16* __restrict__ Ko,
                                                u16* __restrict__ Vo) {
    __shared__ u16 a_lds[128][136];
    __shared__ u16 w_lds[64][136];
    int tid = threadIdx.x;
    int m0 = blockIdx.y * 128, n0 = blockIdx.x * 64;
    #pragma unroll
    for (int i = 0; i < 8; ++i) {
        int idx = tid + 256 * i;
        int row = idx >> 4, c8 = (idx & 15) * 8;
        *(int4*)&a_lds[row][c8] = *(const int4*)&X[(size_t)(m0 + row) * 128 + c8];
    }
    #pragma unroll
    for (int i = 0; i < 8; ++i) {
        int idx = tid + 256 * i;
        int row = idx >> 5, c4 = (idx & 31) * 4;
        float4 f = *(const float4*)&Wn[(size_t)(n0 + row) * 128 + c4];
        uint2 p;
        p.x = (unsigned)f2bf(f.x) | ((unsigned)f2bf(f.y) << 16);
        p.y = (unsigned)f2bf(f.z) | ((unsigned)f2bf(f.w) << 16);
        *(uint2*)&w_lds[row][c4] = p;
    }
    __syncthreads();
    int lane = tid & 63, wid = tid >> 6;
    int wr = (wid >> 1) * 64, wc = (wid & 1) * 32;
    int kg = lane >> 4, l15 = lane & 15;
    f32x4 acc[4][2];
    #pragma unroll
    for (int i = 0; i < 4; ++i)
        #pragma unroll
        for (int j = 0; j < 2; ++j) acc[i][j] = (f32x4){0.f, 0.f, 0.f, 0.f};
    #pragma unroll
    for (int kk = 0; kk < 4; ++kk) {
        int kof = kk * 32 + kg * 8;
        bf16x8 a[4], b[2];
        #pragma unroll
        for (int i = 0; i < 4; ++i) a[i] = *(const bf16x8*)&a_lds[wr + i * 16 + l15][kof];
        #pragma unroll
        for (int j = 0; j < 2; ++j) b[j] = *(const bf16x8*)&w_lds[wc + j * 16 + l15][kof];
        #pragma unroll
        for (int i = 0; i < 4; ++i)
            #pragma unroll
            for (int j = 0; j < 2; ++j)
                acc[i][j] = __builtin_amdgcn_mfma_f32_16x16x32_bf16(a[i], b[j], acc[i][j], 0, 0, 0);
    }
    #pragma unroll
    for (int i = 0; i < 4; ++i)
        #pragma unroll
        for (int j = 0; j < 2; ++j) {
            int col_g = n0 + wc + j * 16 + l15;
            float bv = bias[col_g];
            int which = col_g >> 7, e = (col_g >> 4) & 7, d = col_g & 15;
            u16* dst = which == 0 ? Qo : (which == 1 ? Ko : Vo);
            float scl = which == 0 ? 0.25f : 1.0f;
            #pragma unroll
            for (int ii = 0; ii < 4; ++ii) {
                int row_g = m0 + wr + i * 16 + kg * 4 + ii;
                int batch = row_g % 384, sq = row_g / 384;
                dst[((size_t)(batch * 8 + e) * 192 + sq) * 16 + d] = f2bf((acc[i][j][ii] + bv) * scl);
            }
        }
}

// ---------------- fused rel-pos attention per (batch, head, w-half) -----------
// scores[w][v] = Q[w]·K[v] + Q[w]·kr[w-v+191] + K[v]·qr[w-v+191]
// v chunked 2x96 (no-max softmax => exact chunked accumulation); per chunk:
// A (store) | B (+=) | C (+=) | exp+pack (float-typed in-place) | PV (reg acc).
// sc row 96 = dump row, col 96 = dump col (OOB clamps; garbage races harmless).
// No atomics, no asm memory clobbers (R5-R7 spill lesson).
__global__ __launch_bounds__(512, 4) void attn_kernel(const u16* __restrict__ Qg,
                                                      const u16* __restrict__ Kg,
                                                      const u16* __restrict__ Vg,
                                                      const u16* __restrict__ qr_g,
                                                      const u16* __restrict__ kr_g,
                                                      u16* __restrict__ Og) {
    __shared__ float sc[97][100];   // 38800 B
    __shared__ u16 Vt[16][200];     // 6400 B
    __shared__ float rsum[96];
    int tid = threadIdx.x, lane = tid & 63, wid = tid >> 6;
    int half = blockIdx.x, e = blockIdx.y, b = blockIdx.z;
    int w0 = half * 96;
    size_t base = ((size_t)b * 8 + e) * 192 * 16;

    // stage V^T (16 x 192)
    #pragma unroll
    for (int i = 0; i < 6; ++i) { int idx = tid + 512 * i;
        Vt[idx & 15][idx >> 4] = Vg[base + idx]; }
    if (tid < 96) rsum[tid] = 0.f;
    __syncthreads();

    int lo = lane & 31, hi = lane >> 5, hi8 = hi * 8;
    int l15 = lane & 15, kg = lane >> 4;
    const u16* Qrow  = Qg + base;
    const u16* Krow  = Kg + base;
    const u16* krrow = kr_g + (size_t)e * 384 * 16;
    const u16* qrrow = qr_g + (size_t)e * 384 * 16;
    f32x4 oacc = (f32x4){0.f, 0.f, 0.f, 0.f};

    for (int ch = 0; ch < 2; ++ch) {
        int v0 = ch * 96;

        // ---- Phase A: sc[w][v-v0] = Q·K^T  (A=K,B=Q; 9 tiles; pure stores) ----
        for (int t = wid; t < 9; t += 8) {
            int wt = t / 3, vt = t % 3;
            bf16x8 ak = *(const bf16x8*)(Krow + (size_t)(v0 + vt * 32 + lo) * 16 + hi8);
            bf16x8 bq = *(const bf16x8*)(Qrow + (size_t)(w0 + wt * 32 + lo) * 16 + hi8);
            f32x16 acc = {};
            acc = __builtin_amdgcn_mfma_f32_32x32x16_bf16(ak, bq, acc, 0, 0, 0);
            float* dst = &sc[wt * 32 + lo][vt * 32 + 4 * hi];
            #pragma unroll
            for (int g = 0; g < 4; ++g) {
                f32x4 vv = { acc[4 * g], acc[4 * g + 1], acc[4 * g + 2], acc[4 * g + 3] };
                *(f32x4*)(dst + 8 * g) = vv;
            }
        }
        __syncthreads();

        // ---- Phase B: sc[w][c] += (Q·kr^T)[w, w+191-(v0+c)]  (12 tiles) ----
        for (int t = wid; t < 12; t += 8) {
            int wt = t >> 2, dt = t & 3;
            int D0 = w0 + 32 * wt + 96 - v0 + 32 * dt;
            bf16x8 akr = *(const bf16x8*)(krrow + (size_t)(D0 + lo) * 16 + hi8);
            bf16x8 bq  = *(const bf16x8*)(Qrow + (size_t)(w0 + wt * 32 + lo) * 16 + hi8);
            f32x16 acc = {};
            acc = __builtin_amdgcn_mfma_f32_32x32x16_bf16(akr, bq, acc, 0, 0, 0);
            int row = wt * 32 + lo;
            int cb = lo + 95 - 32 * dt - 4 * hi;     // c = cb - rr
            if (dt == 1 || dt == 2) {
                float* rowp = &sc[row][0];
                #pragma unroll
                for (int ii = 0; ii < 16; ++ii) {
                    const int rr = (ii & 3) + 8 * (ii >> 2);
                    rowp[cb - rr] += acc[ii];
                }
            } else {
                float* rowp = &sc[row][0];
                #pragma unroll
                for (int ii = 0; ii < 16; ++ii) {
                    const int rr = (ii & 3) + 8 * (ii >> 2);
                    int c = cb - rr;
                    int col = ((unsigned)c < 96u) ? c : 96;
                    rowp[col] += acc[ii];
                }
            }
        }
        __syncthreads();

        // ---- Phase C: sc[r][c] += K[v0+c]·qr[w+191-v]  (12 tiles) ----
        for (int t = wid; t < 12; t += 8) {
            int vt = t >> 2, dt = t & 3;
            int D0 = w0 - v0 - 32 * vt + 160 + 32 * dt;
            bf16x8 aqr = *(const bf16x8*)(qrrow + (size_t)(D0 + lo) * 16 + hi8);
            bf16x8 bk  = *(const bf16x8*)(Krow + (size_t)(v0 + vt * 32 + lo) * 16 + hi8);
            f32x16 acc = {};
            acc = __builtin_amdgcn_mfma_f32_32x32x16_bf16(aqr, bk, acc, 0, 0, 0);
            int c = vt * 32 + lo;
            int rb = 32 * dt - 31 + lo + 4 * hi;     // r = rb + rr
            if (dt == 1 || dt == 2) {
                #pragma unroll
                for (int ii = 0; ii < 16; ++ii) {
                    const int rr = (ii & 3) + 8 * (ii >> 2);
                    sc[rb + rr][c] += acc[ii];
                }
            } else {
                #pragma unroll
                for (int ii = 0; ii < 16; ++ii) {
                    const int rr = (ii & 3) + 8 * (ii >> 2);
                    int r = rb + rr;
                    int rowi = ((unsigned)r < 96u) ? r : 96;
                    sc[rowi][c] += acc[ii];
                }
            }
        }
        __syncthreads();

        // ---- exp + pack in place (float-typed stores); rsum += ----
        {
            int r = tid >> 2, j = tid & 3;
            if (r < 96) {
                float* srow = &sc[r][j * 24];
                f32x4 X[6];
                #pragma unroll
                for (int k = 0; k < 6; ++k) X[k] = *(const f32x4*)&srow[k * 4];
                float xs[24];
                #pragma unroll
                for (int k = 0; k < 6; ++k) {
                    xs[4 * k]     = __expf(X[k][0]);
                    xs[4 * k + 1] = __expf(X[k][1]);
                    xs[4 * k + 2] = __expf(X[k][2]);
                    xs[4 * k + 3] = __expf(X[k][3]);
                }
                float sum = 0.f;
                #pragma unroll
                for (int k = 0; k < 24; ++k) sum += xs[k];
                f32x4 pkv[3];
                #pragma unroll
                for (int g = 0; g < 3; ++g)
                    #pragma unroll
                    for (int k = 0; k < 4; ++k)
                        pkv[g][k] = __uint_as_float(cvt_pk_bf16(xs[8 * g + 2 * k], xs[8 * g + 2 * k + 1]));
                float* prow = &sc[r][12 * j];
                *(f32x4*)&prow[0] = pkv[0];
                *(f32x4*)&prow[4] = pkv[1];
                *(f32x4*)&prow[8] = pkv[2];
                sum += __shfl_xor(sum, 1);
                sum += __shfl_xor(sum, 2);
                if (j == 0) rsum[r] += sum;
            }
        }
        __syncthreads();

        // ---- PV: oacc += P_chunk · V_chunk  (waves 0..5, 16x16x32 over v) ----
        if (wid < 6) {
            const u16* prow = (const u16*)&sc[wid * 16 + l15][0];
            #pragma unroll
            for (int kt = 0; kt < 3; ++kt) {
                bf16x8 a  = *(const bf16x8*)(prow + kt * 32 + kg * 8);
                bf16x8 bb = *(const bf16x8*)&Vt[l15][v0 + kt * 32 + kg * 8];
                oacc = __builtin_amdgcn_mfma_f32_16x16x32_bf16(a, bb, oacc, 0, 0, 0);
            }
        }
        __syncthreads();   // sc reused by next chunk's phase A
    }

    if (wid < 6) {
        #pragma unroll
        for (int ii = 0; ii < 4; ++ii) {
            int wl = wid * 16 + kg * 4 + ii;
            float val = oacc[ii] * (1.0f / rsum[wl]);
            Og[((size_t)(w0 + wl) * 384 + b) * 128 + e * 16 + l15] = f2bf(val);
        }
    }
}

// ---------------- output projection GEMM -------------------------------------
// MODE 0: x1[(w*384+s*192+h)] = O_row(h*384+s*192+w) @ w_out^T + b   (bf16)
// MODE 1: out[row] = O_row @ w_out^T + b + feat[row]                 (fp32)
template <int MODE>
__global__ __launch_bounds__(256) void outproj_gemm(const u16* __restrict__ X,
                                                    const float* __restrict__ Wn,
                                                    const float* __restrict__ bias,
                                                    const float* __restrict__ feat,
                                                    u16* __restrict__ x1o,
                                                    float* __restrict__ outp) {
    __shared__ u16 a_lds[128][136];
    __shared__ u16 w_lds[64][136];
    int tid = threadIdx.x;
    int m0 = blockIdx.y * 128, n0 = blockIdx.x * 64;
    #pragma unroll
    for (int i = 0; i < 8; ++i) {
        int idx = tid + 256 * i;
        int row = idx >> 4, c8 = (idx & 15) * 8;
        *(int4*)&a_lds[row][c8] = *(const int4*)&X[(size_t)(m0 + row) * 128 + c8];
    }
    #pragma unroll
    for (int i = 0; i < 8; ++i) {
        int idx = tid + 256 * i;
        int row = idx >> 5, c4 = (idx & 31) * 4;
        float4 f = *(const float4*)&Wn[(size_t)(n0 + row) * 128 + c4];
        uint2 p;
        p.x = (unsigned)f2bf(f.x) | ((unsigned)f2bf(f.y) << 16);
        p.y = (unsigned)f2bf(f.z) | ((unsigned)f2bf(f.w) << 16);
        *(uint2*)&w_lds[row][c4] = p;
    }
    __syncthreads();
    int lane = tid & 63, wid = tid >> 6;
    int wr = (wid >> 1) * 64, wc = (wid & 1) * 32;
    int kg = lane >> 4, l15 = lane & 15;
    f32x4 acc[4][2];
    #pragma unroll
    for (int i = 0; i < 4; ++i)
        #pragma unroll
        for (int j = 0; j < 2; ++j) acc[i][j] = (f32x4){0.f, 0.f, 0.f, 0.f};
    #pragma unroll
    for (int kk = 0; kk < 4; ++kk) {
        int kof = kk * 32 + kg * 8;
        bf16x8 a[4], b[2];
        #pragma unroll
        for (int i = 0; i < 4; ++i) a[i] = *(const bf16x8*)&a_lds[wr + i * 16 + l15][kof];
        #pragma unroll
        for (int j = 0; j < 2; ++j) b[j] = *(const bf16x8*)&w_lds[wc + j * 16 + l15][kof];
        #pragma unroll
        for (int i = 0; i < 4; ++i)
            #pragma unroll
            for (int j = 0; j < 2; ++j)
                acc[i][j] = __builtin_amdgcn_mfma_f32_16x16x32_bf16(a[i], b[j], acc[i][j], 0, 0, 0);
    }
    #pragma unroll
    for (int i = 0; i < 4; ++i)
        #pragma unroll
        for (int j = 0; j < 2; ++j) {
            int col_g = n0 + wc + j * 16 + l15;
            float bv = bias[col_g];
            #pragma unroll
            for (int ii = 0; ii < 4; ++ii) {
                int row_g = m0 + wr + i * 16 + kg * 4 + ii;
                float val = acc[i][j][ii] + bv;
                if (MODE == 0) {
                    int h = row_g / 384, rem = row_g % 384, s2 = rem / 192, w = rem % 192;
                    x1o[((size_t)(w * 384 + s2 * 192 + h)) * 128 + col_g] = f2bf(val);
                } else {
                    size_t o = (size_t)row_g * 128 + col_g;
                    outp[o] = val + feat[o];
                }
            }
        }
}

extern "C" void kernel_launch(void* const* d_in, const int* in_sizes, int n_in,
                              void* d_out, int out_size, void* d_ws, size_t ws_size,
                              hipStream_t stream) {
    const float* feat   = (const float*)d_in[0];
    const float* pos    = (const float*)d_in[1];
    const float* pos_y  = (const float*)d_in[2];
    const float* ln_w   = (const float*)d_in[3];
    const float* ln_b   = (const float*)d_in[4];
    const float* w_in1  = (const float*)d_in[5];
    const float* b_in1  = (const float*)d_in[6];
    const float* w_out1 = (const float*)d_in[7];
    const float* b_out1 = (const float*)d_in[8];
    const float* w_in2  = (const float*)d_in[9];
    const float* b_in2  = (const float*)d_in[10];
    const float* w_out2 = (const float*)d_in[11];
    const float* b_out2 = (const float*)d_in[12];
    float* out = (float*)d_out;

    char* ws = (char*)d_ws;
    const size_t R = (size_t)73728 * 128;   // 9,437,184 elements
    u16* x2 = (u16*)ws; ws += R * 2;
    u16* x1 = (u16*)ws; ws += R * 2;
    u16* Q  = (u16*)ws; ws += R * 2;
    u16* K  = (u16*)ws; ws += R * 2;
    u16* V  = (u16*)ws; ws += R * 2;
    u16* O  = (u16*)ws; ws += R * 2;
    u16* qr = (u16*)ws; ws += (size_t)8 * 384 * 16 * 2;
    u16* kr = (u16*)ws; ws += (size_t)8 * 384 * 16 * 2;

    // ---- layer 2 (vertical axis) ----
    ln_kernel<<<18432, 256, 0, stream>>>(feat, ln_w, ln_b, x2);
    posproj_kernel<<<384, 256, 0, stream>>>(pos_y, w_in2, b_in2, qr, kr);
    qkv_gemm<<<dim3(6, 576), 256, 0, stream>>>(x2, w_in2, b_in2, Q, K, V);
    attn_kernel<<<dim3(2, 8, 384), 512, 0, stream>>>(Q, K, V, qr, kr, O);
    outproj_gemm<0><<<dim3(2, 576), 256, 0, stream>>>(O, w_out2, b_out2, nullptr, x1, nullptr);
    // ---- layer 1 (horizontal axis) ----
    posproj_kernel<<<384, 256, 0, stream>>>(pos, w_in1, b_in1, qr, kr);
    qkv_gemm<<<dim3(6, 576), 256, 0, stream>>>(x1, w_in1, b_in1, Q, K, V);
    attn_kernel<<<dim3(2, 8, 384), 512, 0, stream>>>(Q, K, V, qr, kr, O);
    outproj_gemm<1><<<dim3(2, 576), 256, 0, stream>>>(O, w_out1, b_out1, feat, nullptr, out);
}

// Round 9
// 397.998 us; speedup vs baseline: 11.5161x; 1.0970x over previous
//
#include <hip/hip_runtime.h>
#include <hip/hip_bf16.h>

// Axial rel-pos attention, MI355X gfx950.
// Shapes: W=192 seq, B=384 batch (=2*192), C=128, 8 heads, hd=16.

typedef unsigned short u16;
typedef short bf16x8 __attribute__((ext_vector_type(8)));
typedef float f32x4 __attribute__((ext_vector_type(4)));
typedef float f32x16 __attribute__((ext_vector_type(16)));

__device__ inline u16 f2bf(float f) {
    union { float f; unsigned u; } a; a.f = f;
    unsigned u = a.u;
    unsigned r = u + 0x7FFFu + ((u >> 16) & 1u);   // RNE
    return (u16)(r >> 16);
}
__device__ inline unsigned cvt_pk_bf16(float lo, float hi) {
    unsigned r;
    asm("v_cvt_pk_bf16_f32 %0, %1, %2" : "=v"(r) : "v"(lo), "v"(hi));
    return r;
}

// ---------------- LayerNorm + transpose (feat[w,s*192+h] -> x2[h,s*192+w]) ----
__global__ __launch_bounds__(256) void ln_kernel(const float* __restrict__ feat,
                                                 const float* __restrict__ g,
                                                 const float* __restrict__ bta,
                                                 u16* __restrict__ x2) {
    int wid = threadIdx.x >> 6, lane = threadIdx.x & 63;
    int r = blockIdx.x * 4 + wid;                 // 0..73727
    const float* row = feat + (size_t)r * 128;
    float v0 = row[lane], v1 = row[lane + 64];
    float s = v0 + v1;
    for (int m = 1; m < 64; m <<= 1) s += __shfl_xor(s, m);
    float mean = s * (1.0f / 128.0f);
    float d0 = v0 - mean, d1 = v1 - mean;
    float vs = d0 * d0 + d1 * d1;
    for (int m = 1; m < 64; m <<= 1) vs += __shfl_xor(vs, m);
    float rstd = rsqrtf(vs * (1.0f / 128.0f) + 1e-5f);
    int w = r / 384, rem = r % 384;               // rem = s*192 + h
    int out_r = (rem % 192) * 384 + (rem / 192) * 192 + w;
    u16* orow = x2 + (size_t)out_r * 128;
    orow[lane]      = f2bf(d0 * rstd * g[lane] + bta[lane]);
    orow[lane + 64] = f2bf(d1 * rstd * g[lane + 64] + bta[lane + 64]);
}

// ---------------- pos-embedding projection: P = pos @ w_in[:256].T + b ---------
// qr[e][d][j] = P[d, e*16+j]*0.25 ; kr[e][d][j] = P[d, 128+e*16+j]; row 383 = 0.
__global__ __launch_bounds__(256) void posproj_kernel(const float* __restrict__ pos,
                                                      const float* __restrict__ w_in,
                                                      const float* __restrict__ b_in,
                                                      u16* __restrict__ qr,
                                                      u16* __restrict__ kr) {
    int d = blockIdx.x, t = threadIdx.x;
    if (d == 383) {
        if (t < 128)      { int e = t >> 4,  j = t & 15;  qr[(e * 384 + 383) * 16 + j] = 0; }
        else              { int t2 = t - 128; int e = t2 >> 4, j = t2 & 15; kr[(e * 384 + 383) * 16 + j] = 0; }
        return;
    }
    __shared__ float prow[128];
    if (t < 128) prow[t] = pos[d * 128 + t];
    __syncthreads();
    const float* wrow = w_in + t * 128;
    float acc = b_in[t];
    #pragma unroll 8
    for (int k = 0; k < 128; ++k) acc += prow[k] * wrow[k];
    int which = t >> 7, e = (t >> 4) & 7, j = t & 15;
    if (which == 0) qr[(e * 384 + d) * 16 + j] = f2bf(acc * 0.25f);
    else            kr[(e * 384 + d) * 16 + j] = f2bf(acc);
}

// ---------------- QKV GEMM: [73728,128]bf16 @ w_in^T[128,384] + b -------------
// Output scatter to Q/K/V [batch][head][seq][16] bf16, Q pre-scaled by 0.25.
__global__ __launch_bounds__(256) void qkv_gemm(const u16* __restrict__ X,
                                                const float* __restrict__ Wn,
                                                const float* __restrict__ bias,
                                                u16* __restrict__ Qo,
                                                u16* __restrict__ Ko,
                                                u16* __restrict__ Vo) {
    __shared__ u16 a_lds[128][136];
    __shared__ u16 w_lds[64][136];
    int tid = threadIdx.x;
    int m0 = blockIdx.y * 128, n0 = blockIdx.x * 64;
    #pragma unroll
    for (int i = 0; i < 8; ++i) {
        int idx = tid + 256 * i;
        int row = idx >> 4, c8 = (idx & 15) * 8;
        *(int4*)&a_lds[row][c8] = *(const int4*)&X[(size_t)(m0 + row) * 128 + c8];
    }
    #pragma unroll
    for (int i = 0; i < 8; ++i) {
        int idx = tid + 256 * i;
        int row = idx >> 5, c4 = (idx & 31) * 4;
        float4 f = *(const float4*)&Wn[(size_t)(n0 + row) * 128 + c4];
        uint2 p;
        p.x = (unsigned)f2bf(f.x) | ((unsigned)f2bf(f.y) << 16);
        p.y = (unsigned)f2bf(f.z) | ((unsigned)f2bf(f.w) << 16);
        *(uint2*)&w_lds[row][c4] = p;
    }
    __syncthreads();
    int lane = tid & 63, wid = tid >> 6;
    int wr = (wid >> 1) * 64, wc = (wid & 1) * 32;
    int kg = lane >> 4, l15 = lane & 15;
    f32x4 acc[4][2];
    #pragma unroll
    for (int i = 0; i < 4; ++i)
        #pragma unroll
        for (int j = 0; j < 2; ++j) acc[i][j] = (f32x4){0.f, 0.f, 0.f, 0.f};
    #pragma unroll
    for (int kk = 0; kk < 4; ++kk) {
        int kof = kk * 32 + kg * 8;
        bf16x8 a[4], b[2];
        #pragma unroll
        for (int i = 0; i < 4; ++i) a[i] = *(const bf16x8*)&a_lds[wr + i * 16 + l15][kof];
        #pragma unroll
        for (int j = 0; j < 2; ++j) b[j] = *(const bf16x8*)&w_lds[wc + j * 16 + l15][kof];
        #pragma unroll
        for (int i = 0; i < 4; ++i)
            #pragma unroll
            for (int j = 0; j < 2; ++j)
                acc[i][j] = __builtin_amdgcn_mfma_f32_16x16x32_bf16(a[i], b[j], acc[i][j], 0, 0, 0);
    }
    #pragma unroll
    for (int i = 0; i < 4; ++i)
        #pragma unroll
        for (int j = 0; j < 2; ++j) {
            int col_g = n0 + wc + j * 16 + l15;
            float bv = bias[col_g];
            int which = col_g >> 7, e = (col_g >> 4) & 7, d = col_g & 15;
            u16* dst = which == 0 ? Qo : (which == 1 ? Ko : Vo);
            float scl = which == 0 ? 0.25f : 1.0f;
            #pragma unroll
            for (int ii = 0; ii < 4; ++ii) {
                int row_g = m0 + wr + i * 16 + kg * 4 + ii;
                int batch = row_g % 384, sq = row_g / 384;
                dst[((size_t)(batch * 8 + e) * 192 + sq) * 16 + d] = f2bf((acc[i][j][ii] + bv) * scl);
            }
        }
}

// ---------------- fused rel-pos attention per (batch, head, w-third) ----------
// scores[w][v] = Q[w]·K[v] + Q[w]·kr[w-v+191] + K[v]·qr[w-v+191]
// Block = 4 waves, 64 w-rows, v chunked 2x96 (no-max softmax => exact chunks).
// Per chunk: A (store) | bar | B (+=) | bar | C (+=) | bar | exp+pack + PV
// (same-wave rows => no barrier between exp and PV) | bar.
// sc row 64 = dump row, col 96 = dump col. B/C scatter addresses have
// Δlane = 101 ≡ 5 mod 32 -> bank-conflict-free. Rows 16B-aligned (stride 100).
__global__ __launch_bounds__(256, 5) void attn_kernel(const u16* __restrict__ Qg,
                                                      const u16* __restrict__ Kg,
                                                      const u16* __restrict__ Vg,
                                                      const u16* __restrict__ qr_g,
                                                      const u16* __restrict__ kr_g,
                                                      u16* __restrict__ Og) {
    __shared__ float sc[65][100];   // 26000 B
    __shared__ u16 Vt[16][200];     // 6400 B
    __shared__ float rsum[64];
    int tid = threadIdx.x, lane = tid & 63, wid = tid >> 6;   // 4 waves
    int third = blockIdx.x, e = blockIdx.y, b = blockIdx.z;
    int w0 = third * 64;
    size_t base = ((size_t)b * 8 + e) * 192 * 16;

    // stage V^T (16 x 192); covered by the first phase-A barrier
    #pragma unroll
    for (int i = 0; i < 12; ++i) { int idx = tid + 256 * i;
        Vt[idx & 15][idx >> 4] = Vg[base + idx]; }
    if (tid < 64) rsum[tid] = 0.f;

    int lo = lane & 31, hi = lane >> 5, hi8 = hi * 8;
    int l15 = lane & 15, kg = lane >> 4;
    const u16* Qrow  = Qg + base;
    const u16* Krow  = Kg + base;
    const u16* krrow = kr_g + (size_t)e * 384 * 16;
    const u16* qrrow = qr_g + (size_t)e * 384 * 16;
    f32x4 oacc = (f32x4){0.f, 0.f, 0.f, 0.f};

    for (int ch = 0; ch < 2; ++ch) {
        int v0 = ch * 96;

        // ---- Phase A: sc[w][c] = Q·K^T  (A=K reg->v, B=Q lane->w; 6 tiles) ----
        for (int t = wid; t < 6; t += 4) {
            int wt = t / 3, vt = t % 3;
            bf16x8 ak = *(const bf16x8*)(Krow + (size_t)(v0 + vt * 32 + lo) * 16 + hi8);
            bf16x8 bq = *(const bf16x8*)(Qrow + (size_t)(w0 + wt * 32 + lo) * 16 + hi8);
            f32x16 acc = {};
            acc = __builtin_amdgcn_mfma_f32_32x32x16_bf16(ak, bq, acc, 0, 0, 0);
            float* dst = &sc[wt * 32 + lo][vt * 32 + 4 * hi];
            #pragma unroll
            for (int g = 0; g < 4; ++g) {
                f32x4 vv = { acc[4 * g], acc[4 * g + 1], acc[4 * g + 2], acc[4 * g + 3] };
                *(f32x4*)(dst + 8 * g) = vv;
            }
        }
        __syncthreads();

        // ---- Phase B: sc[w][c] += (Q·kr^T)[w, d]  (A=kr reg->d, B=Q; 8 tiles) --
        for (int t = wid; t < 8; t += 4) {
            int wt = t >> 2, dt = t & 3;
            int D0 = w0 + 32 * wt + 96 - v0 + 32 * dt;      // 0 <= D0, D0+31 <= 383
            bf16x8 akr = *(const bf16x8*)(krrow + (size_t)(D0 + lo) * 16 + hi8);
            bf16x8 bq  = *(const bf16x8*)(Qrow + (size_t)(w0 + wt * 32 + lo) * 16 + hi8);
            f32x16 acc = {};
            acc = __builtin_amdgcn_mfma_f32_32x32x16_bf16(akr, bq, acc, 0, 0, 0);
            float* rowp = &sc[wt * 32 + lo][0];
            int cb = lo + 95 - 32 * dt - 4 * hi;            // c = cb - rr
            if (dt == 1 || dt == 2) {
                #pragma unroll
                for (int ii = 0; ii < 16; ++ii) {
                    const int rr = (ii & 3) + 8 * (ii >> 2);
                    rowp[cb - rr] += acc[ii];
                }
            } else {
                #pragma unroll
                for (int ii = 0; ii < 16; ++ii) {
                    const int rr = (ii & 3) + 8 * (ii >> 2);
                    int c = cb - rr;
                    rowp[((unsigned)c < 96u) ? c : 96] += acc[ii];
                }
            }
        }
        __syncthreads();

        // ---- Phase C: sc[r][c] += K[v]·qr[d]  (A=qr reg->d, B=K; 9 tiles) ----
        for (int t = wid; t < 9; t += 4) {
            int vt = t / 3, dt = t % 3;
            int D0 = w0 + 160 - v0 - 32 * vt + 32 * dt;     // 0 <= D0, D0+31 <= 383
            bf16x8 aqr = *(const bf16x8*)(qrrow + (size_t)(D0 + lo) * 16 + hi8);
            bf16x8 bk  = *(const bf16x8*)(Krow + (size_t)(v0 + vt * 32 + lo) * 16 + hi8);
            f32x16 acc = {};
            acc = __builtin_amdgcn_mfma_f32_32x32x16_bf16(aqr, bk, acc, 0, 0, 0);
            int c = vt * 32 + lo;
            int rb = 32 * dt - 31 + lo + 4 * hi;            // wloc = rb + rr
            if (dt == 1) {
                #pragma unroll
                for (int ii = 0; ii < 16; ++ii) {
                    const int rr = (ii & 3) + 8 * (ii >> 2);
                    sc[rb + rr][c] += acc[ii];
                }
            } else {
                #pragma unroll
                for (int ii = 0; ii < 16; ++ii) {
                    const int rr = (ii & 3) + 8 * (ii >> 2);
                    int r = rb + rr;
                    sc[((unsigned)r < 64u) ? r : 64][c] += acc[ii];
                }
            }
        }
        __syncthreads();

        // ---- exp + pack in place (all 256 threads, 4 per row) ----
        {
            int r = tid >> 2, j = tid & 3;
            float* srow = &sc[r][j * 24];
            f32x4 X0 = *(const f32x4*)&srow[0];
            f32x4 X1 = *(const f32x4*)&srow[4];
            f32x4 X2 = *(const f32x4*)&srow[8];
            f32x4 X3 = *(const f32x4*)&srow[12];
            f32x4 X4 = *(const f32x4*)&srow[16];
            f32x4 X5 = *(const f32x4*)&srow[20];
            float xs[24];
            #pragma unroll
            for (int k = 0; k < 4; ++k) {
                xs[k]      = __expf(X0[k]);
                xs[4 + k]  = __expf(X1[k]);
                xs[8 + k]  = __expf(X2[k]);
                xs[12 + k] = __expf(X3[k]);
                xs[16 + k] = __expf(X4[k]);
                xs[20 + k] = __expf(X5[k]);
            }
            float sum = 0.f;
            #pragma unroll
            for (int k = 0; k < 24; ++k) sum += xs[k];
            f32x4 pkv[3];
            #pragma unroll
            for (int g = 0; g < 3; ++g)
                #pragma unroll
                for (int k = 0; k < 4; ++k)
                    pkv[g][k] = __uint_as_float(cvt_pk_bf16(xs[8 * g + 2 * k], xs[8 * g + 2 * k + 1]));
            float* prow = &sc[r][12 * j];
            *(f32x4*)&prow[0] = pkv[0];
            *(f32x4*)&prow[4] = pkv[1];
            *(f32x4*)&prow[8] = pkv[2];
            sum += __shfl_xor(sum, 1);
            sum += __shfl_xor(sum, 2);
            if (j == 0) rsum[r] += sum;
        }
        // no barrier: PV wave reads only its own wave's rows

        // ---- PV: oacc += P_chunk · V_chunk  (wave wid owns rows 16wid..+16) ----
        {
            const u16* prow = (const u16*)&sc[wid * 16 + l15][0];
            #pragma unroll
            for (int kt = 0; kt < 3; ++kt) {
                bf16x8 a  = *(const bf16x8*)(prow + kt * 32 + kg * 8);
                bf16x8 bb = *(const bf16x8*)&Vt[l15][v0 + kt * 32 + kg * 8];
                oacc = __builtin_amdgcn_mfma_f32_16x16x32_bf16(a, bb, oacc, 0, 0, 0);
            }
        }
        __syncthreads();   // sc reused by next chunk's phase A
    }

    #pragma unroll
    for (int ii = 0; ii < 4; ++ii) {
        int wl = wid * 16 + kg * 4 + ii;
        float val = oacc[ii] * (1.0f / rsum[wl]);
        Og[((size_t)(w0 + wl) * 384 + b) * 128 + e * 16 + l15] = f2bf(val);
    }
}

// ---------------- output projection GEMM -------------------------------------
// MODE 0: x1[(w*384+s*192+h)] = O_row(h*384+s*192+w) @ w_out^T + b   (bf16)
// MODE 1: out[row] = O_row @ w_out^T + b + feat[row]                 (fp32)
template <int MODE>
__global__ __launch_bounds__(256) void outproj_gemm(const u16* __restrict__ X,
                                                    const float* __restrict__ Wn,
                                                    const float* __restrict__ bias,
                                                    const float* __restrict__ feat,
                                                    u16* __restrict__ x1o,
                                                    float* __restrict__ outp) {
    __shared__ u16 a_lds[128][136];
    __shared__ u16 w_lds[64][136];
    int tid = threadIdx.x;
    int m0 = blockIdx.y * 128, n0 = blockIdx.x * 64;
    #pragma unroll
    for (int i = 0; i < 8; ++i) {
        int idx = tid + 256 * i;
        int row = idx >> 4, c8 = (idx & 15) * 8;
        *(int4*)&a_lds[row][c8] = *(const int4*)&X[(size_t)(m0 + row) * 128 + c8];
    }
    #pragma unroll
    for (int i = 0; i < 8; ++i) {
        int idx = tid + 256 * i;
        int row = idx >> 5, c4 = (idx & 31) * 4;
        float4 f = *(const float4*)&Wn[(size_t)(n0 + row) * 128 + c4];
        uint2 p;
        p.x = (unsigned)f2bf(f.x) | ((unsigned)f2bf(f.y) << 16);
        p.y = (unsigned)f2bf(f.z) | ((unsigned)f2bf(f.w) << 16);
        *(uint2*)&w_lds[row][c4] = p;
    }
    __syncthreads();
    int lane = tid & 63, wid = tid >> 6;
    int wr = (wid >> 1) * 64, wc = (wid & 1) * 32;
    int kg = lane >> 4, l15 = lane & 15;
    f32x4 acc[4][2];
    #pragma unroll
    for (int i = 0; i < 4; ++i)
        #pragma unroll
        for (int j = 0; j < 2; ++j) acc[i][j] = (f32x4){0.f, 0.f, 0.f, 0.f};
    #pragma unroll
    for (int kk = 0; kk < 4; ++kk) {
        int kof = kk * 32 + kg * 8;
        bf16x8 a[4], b[2];
        #pragma unroll
        for (int i = 0; i < 4; ++i) a[i] = *(const bf16x8*)&a_lds[wr + i * 16 + l15][kof];
        #pragma unroll
        for (int j = 0; j < 2; ++j) b[j] = *(const bf16x8*)&w_lds[wc + j * 16 + l15][kof];
        #pragma unroll
        for (int i = 0; i < 4; ++i)
            #pragma unroll
            for (int j = 0; j < 2; ++j)
                acc[i][j] = __builtin_amdgcn_mfma_f32_16x16x32_bf16(a[i], b[j], acc[i][j], 0, 0, 0);
    }
    #pragma unroll
    for (int i = 0; i < 4; ++i)
        #pragma unroll
        for (int j = 0; j < 2; ++j) {
            int col_g = n0 + wc + j * 16 + l15;
            float bv = bias[col_g];
            #pragma unroll
            for (int ii = 0; ii < 4; ++ii) {
                int row_g = m0 + wr + i * 16 + kg * 4 + ii;
                float val = acc[i][j][ii] + bv;
                if (MODE == 0) {
                    int h = row_g / 384, rem = row_g % 384, s2 = rem / 192, w = rem % 192;
                    x1o[((size_t)(w * 384 + s2 * 192 + h)) * 128 + col_g] = f2bf(val);
                } else {
                    size_t o = (size_t)row_g * 128 + col_g;
                    outp[o] = val + feat[o];
                }
            }
        }
}

extern "C" void kernel_launch(void* const* d_in, const int* in_sizes, int n_in,
                              void* d_out, int out_size, void* d_ws, size_t ws_size,
                              hipStream_t stream) {
    const float* feat   = (const float*)d_in[0];
    const float* pos    = (const float*)d_in[1];
    const float* pos_y  = (const float*)d_in[2];
    const float* ln_w   = (const float*)d_in[3];
    const float* ln_b   = (const float*)d_in[4];
    const float* w_in1  = (const float*)d_in[5];
    const float* b_in1  = (const float*)d_in[6];
    const float* w_out1 = (const float*)d_in[7];
    const float* b_out1 = (const float*)d_in[8];
    const float* w_in2  = (const float*)d_in[9];
    const float* b_in2  = (const float*)d_in[10];
    const float* w_out2 = (const float*)d_in[11];
    const float* b_out2 = (const float*)d_in[12];
    float* out = (float*)d_out;

    char* ws = (char*)d_ws;
    const size_t R = (size_t)73728 * 128;   // 9,437,184 elements
    u16* x2 = (u16*)ws; ws += R * 2;
    u16* x1 = (u16*)ws; ws += R * 2;
    u16* Q  = (u16*)ws; ws += R * 2;
    u16* K  = (u16*)ws; ws += R * 2;
    u16* V  = (u16*)ws; ws += R * 2;
    u16* O  = (u16*)ws; ws += R * 2;
    u16* qr = (u16*)ws; ws += (size_t)8 * 384 * 16 * 2;
    u16* kr = (u16*)ws; ws += (size_t)8 * 384 * 16 * 2;

    // ---- layer 2 (vertical axis) ----
    ln_kernel<<<18432, 256, 0, stream>>>(feat, ln_w, ln_b, x2);
    posproj_kernel<<<384, 256, 0, stream>>>(pos_y, w_in2, b_in2, qr, kr);
    qkv_gemm<<<dim3(6, 576), 256, 0, stream>>>(x2, w_in2, b_in2, Q, K, V);
    attn_kernel<<<dim3(3, 8, 384), 256, 0, stream>>>(Q, K, V, qr, kr, O);
    outproj_gemm<0><<<dim3(2, 576), 256, 0, stream>>>(O, w_out2, b_out2, nullptr, x1, nullptr);
    // ---- layer 1 (horizontal axis) ----
    posproj_kernel<<<384, 256, 0, stream>>>(pos, w_in1, b_in1, qr, kr);
    qkv_gemm<<<dim3(6, 576), 256, 0, stream>>>(x1, w_in1, b_in1, Q, K, V);
    attn_kernel<<<dim3(3, 8, 384), 256, 0, stream>>>(Q, K, V, qr, kr, O);
    outproj_gemm<1><<<dim3(2, 576), 256, 0, stream>>>(O, w_out1, b_out1, feat, nullptr, out);
}

// Round 11
// 369.945 us; speedup vs baseline: 12.3894x; 1.0758x over previous
//
#include <hip/hip_runtime.h>
#include <hip/hip_bf16.h>

// Axial rel-pos attention, MI355X gfx950.
// Shapes: W=192 seq, B=384 batch (=2*192), C=128, 8 heads, hd=16.

typedef unsigned short u16;
typedef short bf16x8 __attribute__((ext_vector_type(8)));
typedef float f32x4 __attribute__((ext_vector_type(4)));
typedef float f32x16 __attribute__((ext_vector_type(16)));

#define LOG2E 1.44269504f

__device__ inline u16 f2bf(float f) {
    union { float f; unsigned u; } a; a.f = f;
    unsigned u = a.u;
    unsigned r = u + 0x7FFFu + ((u >> 16) & 1u);   // RNE
    return (u16)(r >> 16);
}
__device__ inline unsigned cvt_pk_bf16(float lo, float hi) {
    unsigned r;
    asm("v_cvt_pk_bf16_f32 %0, %1, %2" : "=v"(r) : "v"(lo), "v"(hi));
    return r;
}
__device__ inline float fast_exp2(float x) {
    return __builtin_amdgcn_exp2f(x);   // v_exp_f32 (base-2)
}

// ---------------- LayerNorm + transpose (feat[w,s*192+h] -> x2[h,s*192+w]) ----
__global__ __launch_bounds__(256) void ln_kernel(const float* __restrict__ feat,
                                                 const float* __restrict__ g,
                                                 const float* __restrict__ bta,
                                                 u16* __restrict__ x2) {
    int wid = threadIdx.x >> 6, lane = threadIdx.x & 63;
    int r = blockIdx.x * 4 + wid;                 // 0..73727
    const float* row = feat + (size_t)r * 128;
    float v0 = row[lane], v1 = row[lane + 64];
    float s = v0 + v1;
    for (int m = 1; m < 64; m <<= 1) s += __shfl_xor(s, m);
    float mean = s * (1.0f / 128.0f);
    float d0 = v0 - mean, d1 = v1 - mean;
    float vs = d0 * d0 + d1 * d1;
    for (int m = 1; m < 64; m <<= 1) vs += __shfl_xor(vs, m);
    float rstd = rsqrtf(vs * (1.0f / 128.0f) + 1e-5f);
    int w = r / 384, rem = r % 384;               // rem = s*192 + h
    int out_r = (rem % 192) * 384 + (rem / 192) * 192 + w;
    u16* orow = x2 + (size_t)out_r * 128;
    orow[lane]      = f2bf(d0 * rstd * g[lane] + bta[lane]);
    orow[lane + 64] = f2bf(d1 * rstd * g[lane + 64] + bta[lane + 64]);
}

// ---------------- pos-embedding projection: P = pos @ w_in[:256].T + b ---------
// qr[e][d][j] = P[d, e*16+j]*0.25*log2e ; kr[e][d][j] = P[d,128+e*16+j]; row 383=0.
__global__ __launch_bounds__(256) void posproj_kernel(const float* __restrict__ pos,
                                                      const float* __restrict__ w_in,
                                                      const float* __restrict__ b_in,
                                                      u16* __restrict__ qr,
                                                      u16* __restrict__ kr) {
    int d = blockIdx.x, t = threadIdx.x;
    if (d == 383) {
        if (t < 128)      { int e = t >> 4,  j = t & 15;  qr[(e * 384 + 383) * 16 + j] = 0; }
        else              { int t2 = t - 128; int e = t2 >> 4, j = t2 & 15; kr[(e * 384 + 383) * 16 + j] = 0; }
        return;
    }
    __shared__ float prow[128];
    if (t < 128) prow[t] = pos[d * 128 + t];
    __syncthreads();
    const float* wrow = w_in + t * 128;
    float acc = b_in[t];
    #pragma unroll 8
    for (int k = 0; k < 128; ++k) acc += prow[k] * wrow[k];
    int which = t >> 7, e = (t >> 4) & 7, j = t & 15;
    if (which == 0) qr[(e * 384 + d) * 16 + j] = f2bf(acc * 0.25f * LOG2E);
    else            kr[(e * 384 + d) * 16 + j] = f2bf(acc);
}

// ---------------- QKV GEMM: [73728,128]bf16 @ w_in^T[128,384] + b -------------
// Output scatter to Q/K/V [batch][head][seq][16] bf16, Q pre-scaled 0.25*log2e.
__global__ __launch_bounds__(256) void qkv_gemm(const u16* __restrict__ X,
                                                const float* __restrict__ Wn,
                                                const float* __restrict__ bias,
                                                u16* __restrict__ Qo,
                                                u16* __restrict__ Ko,
                                                u16* __restrict__ Vo) {
    __shared__ u16 a_lds[128][136];
    __shared__ u16 w_lds[64][136];
    int tid = threadIdx.x;
    int m0 = blockIdx.y * 128, n0 = blockIdx.x * 64;
    #pragma unroll
    for (int i = 0; i < 8; ++i) {
        int idx = tid + 256 * i;
        int row = idx >> 4, c8 = (idx & 15) * 8;
        *(int4*)&a_lds[row][c8] = *(const int4*)&X[(size_t)(m0 + row) * 128 + c8];
    }
    #pragma unroll
    for (int i = 0; i < 8; ++i) {
        int idx = tid + 256 * i;
        int row = idx >> 5, c4 = (idx & 31) * 4;
        float4 f = *(const float4*)&Wn[(size_t)(n0 + row) * 128 + c4];
        uint2 p;
        p.x = (unsigned)f2bf(f.x) | ((unsigned)f2bf(f.y) << 16);
        p.y = (unsigned)f2bf(f.z) | ((unsigned)f2bf(f.w) << 16);
        *(uint2*)&w_lds[row][c4] = p;
    }
    __syncthreads();
    int lane = tid & 63, wid = tid >> 6;
    int wr = (wid >> 1) * 64, wc = (wid & 1) * 32;
    int kg = lane >> 4, l15 = lane & 15;
    f32x4 acc[4][2];
    #pragma unroll
    for (int i = 0; i < 4; ++i)
        #pragma unroll
        for (int j = 0; j < 2; ++j) acc[i][j] = (f32x4){0.f, 0.f, 0.f, 0.f};
    #pragma unroll
    for (int kk = 0; kk < 4; ++kk) {
        int kof = kk * 32 + kg * 8;
        bf16x8 a[4], b[2];
        #pragma unroll
        for (int i = 0; i < 4; ++i) a[i] = *(const bf16x8*)&a_lds[wr + i * 16 + l15][kof];
        #pragma unroll
        for (int j = 0; j < 2; ++j) b[j] = *(const bf16x8*)&w_lds[wc + j * 16 + l15][kof];
        #pragma unroll
        for (int i = 0; i < 4; ++i)
            #pragma unroll
            for (int j = 0; j < 2; ++j)
                acc[i][j] = __builtin_amdgcn_mfma_f32_16x16x32_bf16(a[i], b[j], acc[i][j], 0, 0, 0);
    }
    #pragma unroll
    for (int i = 0; i < 4; ++i)
        #pragma unroll
        for (int j = 0; j < 2; ++j) {
            int col_g = n0 + wc + j * 16 + l15;
            float bv = bias[col_g];
            int which = col_g >> 7, e = (col_g >> 4) & 7, d = col_g & 15;
            u16* dst = which == 0 ? Qo : (which == 1 ? Ko : Vo);
            float scl = which == 0 ? (0.25f * LOG2E) : 1.0f;
            #pragma unroll
            for (int ii = 0; ii < 4; ++ii) {
                int row_g = m0 + wr + i * 16 + kg * 4 + ii;
                int batch = row_g % 384, sq = row_g / 384;
                dst[((size_t)(batch * 8 + e) * 192 + sq) * 16 + d] = f2bf((acc[i][j][ii] + bv) * scl);
            }
        }
}

// ---------------- fused rel-pos attention per (batch, head, w-third) ----------
// scores[w][v] = Q[w]·K[v] + Q[w]·kr[w-v+191] + K[v]·qr[w-v+191] (all *log2e)
// Block = 4 waves, 64 w-rows, v chunked 2x96 (no-max softmax => exact chunks).
// Per chunk: A (store) | bar | B (batched +=) | bar | C (batched +=) | bar |
// exp2+pack + PV (same-wave rows) | bar.
// sc row 64 = dump row, col 96 = dump col.
__global__ __launch_bounds__(256, 5) void attn_kernel(const u16* __restrict__ Qg,
                                                      const u16* __restrict__ Kg,
                                                      const u16* __restrict__ Vg,
                                                      const u16* __restrict__ qr_g,
                                                      const u16* __restrict__ kr_g,
                                                      u16* __restrict__ Og) {
    __shared__ float sc[65][100];   // 26000 B
    __shared__ u16 Vt[16][200];     // 6400 B
    __shared__ float rsum[64];
    int tid = threadIdx.x, lane = tid & 63, wid = tid >> 6;   // 4 waves
    int third = blockIdx.x, e = blockIdx.y, b = blockIdx.z;
    int w0 = third * 64;
    size_t base = ((size_t)b * 8 + e) * 192 * 16;

    // stage V^T (16 x 192) with b64 global loads; covered by first barrier
    #pragma unroll
    for (int i = 0; i < 3; ++i) {
        int q = tid + 256 * i;                 // quad index 0..767
        uint2 two = *(const uint2*)&Vg[base + (size_t)q * 4];
        int v = q >> 2, d0 = (q & 3) * 4;
        Vt[d0][v]     = (u16)(two.x);
        Vt[d0 + 1][v] = (u16)(two.x >> 16);
        Vt[d0 + 2][v] = (u16)(two.y);
        Vt[d0 + 3][v] = (u16)(two.y >> 16);
    }
    if (tid < 64) rsum[tid] = 0.f;

    int lo = lane & 31, hi = lane >> 5, hi8 = hi * 8;
    int l15 = lane & 15, kg = lane >> 4;
    const u16* Qrow  = Qg + base;
    const u16* Krow  = Kg + base;
    const u16* krrow = kr_g + (size_t)e * 384 * 16;
    const u16* qrrow = qr_g + (size_t)e * 384 * 16;
    f32x4 oacc = (f32x4){0.f, 0.f, 0.f, 0.f};

    for (int ch = 0; ch < 2; ++ch) {
        int v0 = ch * 96;

        // ---- Phase A: sc[w][c] = Q·K^T  (A=K reg->v, B=Q lane->w; 6 tiles) ----
        for (int t = wid; t < 6; t += 4) {
            int wt = t / 3, vt = t % 3;
            bf16x8 ak = *(const bf16x8*)(Krow + (size_t)(v0 + vt * 32 + lo) * 16 + hi8);
            bf16x8 bq = *(const bf16x8*)(Qrow + (size_t)(w0 + wt * 32 + lo) * 16 + hi8);
            f32x16 acc = {};
            acc = __builtin_amdgcn_mfma_f32_32x32x16_bf16(ak, bq, acc, 0, 0, 0);
            float* dst = &sc[wt * 32 + lo][vt * 32 + 4 * hi];
            #pragma unroll
            for (int g = 0; g < 4; ++g) {
                f32x4 vv = { acc[4 * g], acc[4 * g + 1], acc[4 * g + 2], acc[4 * g + 3] };
                *(f32x4*)(dst + 8 * g) = vv;
            }
        }
        __syncthreads();

        // ---- Phase B: sc[w][c] += (Q·kr^T)[w, d]  (batched RMW; 8 tiles) ----
        for (int t = wid; t < 8; t += 4) {
            int wt = t >> 2, dt = t & 3;
            int D0 = w0 + 32 * wt + 96 - v0 + 32 * dt;      // 0 <= D0, D0+31 <= 383
            bf16x8 akr = *(const bf16x8*)(krrow + (size_t)(D0 + lo) * 16 + hi8);
            bf16x8 bq  = *(const bf16x8*)(Qrow + (size_t)(w0 + wt * 32 + lo) * 16 + hi8);
            f32x16 acc = {};
            acc = __builtin_amdgcn_mfma_f32_32x32x16_bf16(akr, bq, acc, 0, 0, 0);
            float* rowp = &sc[wt * 32 + lo][0];
            int cb = lo + 95 - 32 * dt - 4 * hi;            // c = cb - rr
            float old[16];
            if (dt == 1 || dt == 2) {
                #pragma unroll
                for (int ii = 0; ii < 16; ++ii) {
                    const int rr = (ii & 3) + 8 * (ii >> 2);
                    old[ii] = rowp[cb - rr];
                }
                __builtin_amdgcn_sched_barrier(0);
                #pragma unroll
                for (int ii = 0; ii < 16; ++ii) {
                    const int rr = (ii & 3) + 8 * (ii >> 2);
                    rowp[cb - rr] = old[ii] + acc[ii];
                }
            } else {
                #pragma unroll
                for (int ii = 0; ii < 16; ++ii) {
                    const int rr = (ii & 3) + 8 * (ii >> 2);
                    int c = cb - rr;
                    old[ii] = rowp[((unsigned)c < 96u) ? c : 96];
                }
                __builtin_amdgcn_sched_barrier(0);
                #pragma unroll
                for (int ii = 0; ii < 16; ++ii) {
                    const int rr = (ii & 3) + 8 * (ii >> 2);
                    int c = cb - rr;
                    rowp[((unsigned)c < 96u) ? c : 96] = old[ii] + acc[ii];
                }
            }
        }
        __syncthreads();

        // ---- Phase C: sc[r][c] += K[v]·qr[d]  (batched RMW; 9 tiles) ----
        for (int t = wid; t < 9; t += 4) {
            int vt = t / 3, dt = t % 3;
            int D0 = w0 + 160 - v0 - 32 * vt + 32 * dt;     // 0 <= D0, D0+31 <= 383
            bf16x8 aqr = *(const bf16x8*)(qrrow + (size_t)(D0 + lo) * 16 + hi8);
            bf16x8 bk  = *(const bf16x8*)(Krow + (size_t)(v0 + vt * 32 + lo) * 16 + hi8);
            f32x16 acc = {};
            acc = __builtin_amdgcn_mfma_f32_32x32x16_bf16(aqr, bk, acc, 0, 0, 0);
            int c = vt * 32 + lo;
            int rb = 32 * dt - 31 + lo + 4 * hi;            // wloc = rb + rr
            float old[16];
            if (dt == 1) {
                #pragma unroll
                for (int ii = 0; ii < 16; ++ii) {
                    const int rr = (ii & 3) + 8 * (ii >> 2);
                    old[ii] = sc[rb + rr][c];
                }
                __builtin_amdgcn_sched_barrier(0);
                #pragma unroll
                for (int ii = 0; ii < 16; ++ii) {
                    const int rr = (ii & 3) + 8 * (ii >> 2);
                    sc[rb + rr][c] = old[ii] + acc[ii];
                }
            } else {
                #pragma unroll
                for (int ii = 0; ii < 16; ++ii) {
                    const int rr = (ii & 3) + 8 * (ii >> 2);
                    int r = rb + rr;
                    old[ii] = sc[((unsigned)r < 64u) ? r : 64][c];
                }
                __builtin_amdgcn_sched_barrier(0);
                #pragma unroll
                for (int ii = 0; ii < 16; ++ii) {
                    const int rr = (ii & 3) + 8 * (ii >> 2);
                    int r = rb + rr;
                    sc[((unsigned)r < 64u) ? r : 64][c] = old[ii] + acc[ii];
                }
            }
        }
        __syncthreads();

        // ---- exp2 + pack in place (all 256 threads, 4 per row) ----
        {
            int r = tid >> 2, j = tid & 3;
            float* srow = &sc[r][j * 24];
            f32x4 X0 = *(const f32x4*)&srow[0];
            f32x4 X1 = *(const f32x4*)&srow[4];
            f32x4 X2 = *(const f32x4*)&srow[8];
            f32x4 X3 = *(const f32x4*)&srow[12];
            f32x4 X4 = *(const f32x4*)&srow[16];
            f32x4 X5 = *(const f32x4*)&srow[20];
            float xs[24];
            #pragma unroll
            for (int k = 0; k < 4; ++k) {
                xs[k]      = fast_exp2(X0[k]);
                xs[4 + k]  = fast_exp2(X1[k]);
                xs[8 + k]  = fast_exp2(X2[k]);
                xs[12 + k] = fast_exp2(X3[k]);
                xs[16 + k] = fast_exp2(X4[k]);
                xs[20 + k] = fast_exp2(X5[k]);
            }
            float sum = 0.f;
            #pragma unroll
            for (int k = 0; k < 24; ++k) sum += xs[k];
            f32x4 pkv[3];
            #pragma unroll
            for (int g = 0; g < 3; ++g)
                #pragma unroll
                for (int k = 0; k < 4; ++k)
                    pkv[g][k] = __uint_as_float(cvt_pk_bf16(xs[8 * g + 2 * k], xs[8 * g + 2 * k + 1]));
            float* prow = &sc[r][12 * j];
            *(f32x4*)&prow[0] = pkv[0];
            *(f32x4*)&prow[4] = pkv[1];
            *(f32x4*)&prow[8] = pkv[2];
            sum += __shfl_xor(sum, 1);
            sum += __shfl_xor(sum, 2);
            if (j == 0) rsum[r] += sum;
        }
        // no barrier: PV wave reads only its own wave's rows

        // ---- PV: oacc += P_chunk · V_chunk  (wave wid owns rows 16wid..+16) ----
        {
            const u16* prow = (const u16*)&sc[wid * 16 + l15][0];
            #pragma unroll
            for (int kt = 0; kt < 3; ++kt) {
                bf16x8 a  = *(const bf16x8*)(prow + kt * 32 + kg * 8);
                bf16x8 bb = *(const bf16x8*)&Vt[l15][v0 + kt * 32 + kg * 8];
                oacc = __builtin_amdgcn_mfma_f32_16x16x32_bf16(a, bb, oacc, 0, 0, 0);
            }
        }
        __syncthreads();   // sc reused by next chunk's phase A
    }

    #pragma unroll
    for (int ii = 0; ii < 4; ++ii) {
        int wl = wid * 16 + kg * 4 + ii;
        float val = oacc[ii] * (1.0f / rsum[wl]);
        Og[((size_t)(w0 + wl) * 384 + b) * 128 + e * 16 + l15] = f2bf(val);
    }
}

// ---------------- output projection GEMM -------------------------------------
// MODE 0: x1[(w*384+s*192+h)] = O_row(h*384+s*192+w) @ w_out^T + b   (bf16)
// MODE 1: out[row] = O_row @ w_out^T + b + feat[row]                 (fp32)
template <int MODE>
__global__ __launch_bounds__(256) void outproj_gemm(const u16* __restrict__ X,
                                                    const float* __restrict__ Wn,
                                                    const float* __restrict__ bias,
                                                    const float* __restrict__ feat,
                                                    u16* __restrict__ x1o,
                                                    float* __restrict__ outp) {
    __shared__ u16 a_lds[128][136];
    __shared__ u16 w_lds[64][136];
    int tid = threadIdx.x;
    int m0 = blockIdx.y * 128, n0 = blockIdx.x * 64;
    #pragma unroll
    for (int i = 0; i < 8; ++i) {
        int idx = tid + 256 * i;
        int row = idx >> 4, c8 = (idx & 15) * 8;
        *(int4*)&a_lds[row][c8] = *(const int4*)&X[(size_t)(m0 + row) * 128 + c8];
    }
    #pragma unroll
    for (int i = 0; i < 8; ++i) {
        int idx = tid + 256 * i;
        int row = idx >> 5, c4 = (idx & 31) * 4;
        float4 f = *(const float4*)&Wn[(size_t)(n0 + row) * 128 + c4];
        uint2 p;
        p.x = (unsigned)f2bf(f.x) | ((unsigned)f2bf(f.y) << 16);
        p.y = (unsigned)f2bf(f.z) | ((unsigned)f2bf(f.w) << 16);
        *(uint2*)&w_lds[row][c4] = p;
    }
    __syncthreads();
    int lane = tid & 63, wid = tid >> 6;
    int wr = (wid >> 1) * 64, wc = (wid & 1) * 32;
    int kg = lane >> 4, l15 = lane & 15;
    f32x4 acc[4][2];
    #pragma unroll
    for (int i = 0; i < 4; ++i)
        #pragma unroll
        for (int j = 0; j < 2; ++j) acc[i][j] = (f32x4){0.f, 0.f, 0.f, 0.f};
    #pragma unroll
    for (int kk = 0; kk < 4; ++kk) {
        int kof = kk * 32 + kg * 8;
        bf16x8 a[4], b[2];
        #pragma unroll
        for (int i = 0; i < 4; ++i) a[i] = *(const bf16x8*)&a_lds[wr + i * 16 + l15][kof];
        #pragma unroll
        for (int j = 0; j < 2; ++j) b[j] = *(const bf16x8*)&w_lds[wc + j * 16 + l15][kof];
        #pragma unroll
        for (int i = 0; i < 4; ++i)
            #pragma unroll
            for (int j = 0; j < 2; ++j)
                acc[i][j] = __builtin_amdgcn_mfma_f32_16x16x32_bf16(a[i], b[j], acc[i][j], 0, 0, 0);
    }
    #pragma unroll
    for (int i = 0; i < 4; ++i)
        #pragma unroll
        for (int j = 0; j < 2; ++j) {
            int col_g = n0 + wc + j * 16 + l15;
            float bv = bias[col_g];
            #pragma unroll
            for (int ii = 0; ii < 4; ++ii) {
                int row_g = m0 + wr + i * 16 + kg * 4 + ii;
                float val = acc[i][j][ii] + bv;
                if (MODE == 0) {
                    int h = row_g / 384, rem = row_g % 384, s2 = rem / 192, w = rem % 192;
                    x1o[((size_t)(w * 384 + s2 * 192 + h)) * 128 + col_g] = f2bf(val);
                } else {
                    size_t o = (size_t)row_g * 128 + col_g;
                    outp[o] = val + feat[o];
                }
            }
        }
}

extern "C" void kernel_launch(void* const* d_in, const int* in_sizes, int n_in,
                              void* d_out, int out_size, void* d_ws, size_t ws_size,
                              hipStream_t stream) {
    const float* feat   = (const float*)d_in[0];
    const float* pos    = (const float*)d_in[1];
    const float* pos_y  = (const float*)d_in[2];
    const float* ln_w   = (const float*)d_in[3];
    const float* ln_b   = (const float*)d_in[4];
    const float* w_in1  = (const float*)d_in[5];
    const float* b_in1  = (const float*)d_in[6];
    const float* w_out1 = (const float*)d_in[7];
    const float* b_out1 = (const float*)d_in[8];
    const float* w_in2  = (const float*)d_in[9];
    const float* b_in2  = (const float*)d_in[10];
    const float* w_out2 = (const float*)d_in[11];
    const float* b_out2 = (const float*)d_in[12];
    float* out = (float*)d_out;

    char* ws = (char*)d_ws;
    const size_t R = (size_t)73728 * 128;   // 9,437,184 elements
    u16* x2 = (u16*)ws; ws += R * 2;
    u16* x1 = (u16*)ws; ws += R * 2;
    u16* Q  = (u16*)ws; ws += R * 2;
    u16* K  = (u16*)ws; ws += R * 2;
    u16* V  = (u16*)ws; ws += R * 2;
    u16* O  = (u16*)ws; ws += R * 2;
    u16* qr = (u16*)ws; ws += (size_t)8 * 384 * 16 * 2;
    u16* kr = (u16*)ws; ws += (size_t)8 * 384 * 16 * 2;

    // ---- layer 2 (vertical axis) ----
    ln_kernel<<<18432, 256, 0, stream>>>(feat, ln_w, ln_b, x2);
    posproj_kernel<<<384, 256, 0, stream>>>(pos_y, w_in2, b_in2, qr, kr);
    qkv_gemm<<<dim3(6, 576), 256, 0, stream>>>(x2, w_in2, b_in2, Q, K, V);
    attn_kernel<<<dim3(3, 8, 384), 256, 0, stream>>>(Q, K, V, qr, kr, O);
    outproj_gemm<0><<<dim3(2, 576), 256, 0, stream>>>(O, w_out2, b_out2, nullptr, x1, nullptr);
    // ---- layer 1 (horizontal axis) ----
    posproj_kernel<<<384, 256, 0, stream>>>(pos, w_in1, b_in1, qr, kr);
    qkv_gemm<<<dim3(6, 576), 256, 0, stream>>>(x1, w_in1, b_in1, Q, K, V);
    attn_kernel<<<dim3(3, 8, 384), 256, 0, stream>>>(Q, K, V, qr, kr, O);
    outproj_gemm<1><<<dim3(2, 576), 256, 0, stream>>>(O, w_out1, b_out1, feat, nullptr, out);
}